// Round 21
// baseline (1129.420 us; speedup 1.0000x reference)
//
#include <hip/hip_runtime.h>
#include <math.h>

#define TPB 256
#define NBMAX 2048          // buckets of 128 nodes -> supports N <= 262144

__device__ __forceinline__ float fsig(float x) {
    return __builtin_amdgcn_rcpf(1.f + __expf(-x));   // abs err ~1e-7; x->-inf => 0
}
__device__ __forceinline__ float ftanh(float x) {
    float t = __expf(2.f * fabsf(x));                  // t -> inf => r -> 1
    float r = 1.f - 2.f * __builtin_amdgcn_rcpf(t + 1.f);
    return copysignf(r, x);
}

__global__ __launch_bounds__(256) void k_zero(int* __restrict__ p, int n) {
    int i = blockIdx.x * 256 + threadIdx.x;
    if (i < n) p[i] = 0;
}

// ---------------- bucketed edge binning (128-node buckets) ----------------

__global__ __launch_bounds__(256) void k_bhist(const int* __restrict__ ei,
                                               int* __restrict__ bhist, int E, int NB) {
    __shared__ int h[NBMAX];
    for (int i = threadIdx.x; i < NB; i += 256) h[i] = 0;
    __syncthreads();
    int stride = gridDim.x * 256;
    for (int e = blockIdx.x * 256 + threadIdx.x; e < E; e += stride)
        atomicAdd(&h[ei[E + e] >> 7], 1);
    __syncthreads();
    for (int i = threadIdx.x; i < NB; i += 256) if (h[i]) atomicAdd(&bhist[i], h[i]);
}

__global__ __launch_bounds__(256) void k_bscan(const int* __restrict__ bhist,
                                               int* __restrict__ bbase, int* __restrict__ bfill,
                                               int NB, int E) {
    __shared__ int tsum[256];
    int tid = threadIdx.x;
    int per = (NB + 255) / 256;           // <= 8
    int loc[8]; int tot = 0;
    int base = tid * per;
#pragma unroll
    for (int j = 0; j < 8; j++) {
        int i = base + j;
        int v = (j < per && i < NB) ? bhist[i] : 0;
        loc[j] = v; tot += v;
    }
    tsum[tid] = tot;
    __syncthreads();
    for (int off = 1; off < 256; off <<= 1) {
        int t = (tid >= off) ? tsum[tid - off] : 0;
        __syncthreads();
        tsum[tid] += t;
        __syncthreads();
    }
    int run = tsum[tid] - tot;
#pragma unroll
    for (int j = 0; j < 8; j++) {
        int i = base + j;
        if (j < per && i < NB) { bbase[i] = run; bfill[i] = run; run += loc[j]; }
    }
    if (tid == 0) bbase[NB] = E;
}

__global__ __launch_bounds__(256) void k_bin(const int* __restrict__ ei,
                                             const float* __restrict__ ew,
                                             int* bfill, int2* __restrict__ ebuf,
                                             int E, int NB) {
    __shared__ int h[NBMAX];
    __shared__ int gb[NBMAX];
    const int EPT = 16;
    int tid = threadIdx.x;
    int base = blockIdx.x * 256 * EPT;
    for (int i = tid; i < NB; i += 256) h[i] = 0;
    __syncthreads();
    int src[EPT]; float w[EPT]; int bkt[EPT]; int lrank[EPT];
#pragma unroll
    for (int j = 0; j < EPT; j++) {
        int e = base + j * 256 + tid;              // coalesced
        if (e < E) {
            src[j] = ei[e]; int d = ei[E + e]; w[j] = ew[e];
            int b = d >> 7;
            bkt[j] = b | ((d & 127) << 16);
            lrank[j] = atomicAdd(&h[b], 1);
        } else bkt[j] = -1;
    }
    __syncthreads();
    for (int i = tid; i < NB; i += 256) gb[i] = h[i] ? atomicAdd(&bfill[i], h[i]) : 0;
    __syncthreads();
#pragma unroll
    for (int j = 0; j < EPT; j++) {
        if (bkt[j] >= 0) {
            int b = bkt[j] & 0xFFFF, dlow = (bkt[j] >> 16) & 0x7F;
            int2 v; v.x = src[j] | (dlow << 24); v.y = __float_as_int(w[j]);
            ebuf[gb[b] + lrank[j]] = v;
        }
    }
}

// per bucket (128 nodes): wsum via native ds_add -> dinv; fused Y = dinv*X.
// No edge scatter at all (layer kernel consumes ebuf directly).
__global__ __launch_bounds__(256) void k_bucket(const int2* __restrict__ ebuf,
                                                const int* __restrict__ bbase,
                                                float* __restrict__ dinv,
                                                const float4* __restrict__ X4,
                                                float4* __restrict__ Y4,
                                                int N, int E) {
    __shared__ float wsum[128];
    __shared__ float sdinv[128];
    int b = blockIdx.x, tid = threadIdx.x;
    int beg = bbase[b], end = bbase[b + 1];
    if (tid < 128) wsum[tid] = 0.f;
    __syncthreads();
    for (int i = beg + tid; i < end; i += 256) {
        int2 v = ebuf[i];
        int dlow = ((unsigned)v.x) >> 24;
        unsafeAtomicAdd(&wsum[dlow], __int_as_float(v.y));   // native ds_add_f32
    }
    __syncthreads();
    if (tid < 128) {
        float dv = rsqrtf(1.0f + wsum[tid]);       // self-loop weight 1; deg >= 1
        sdinv[tid] = dv;
        int node = (b << 7) + tid;
        if (node < N) dinv[node] = dv;
    }
    __syncthreads();
    int nNodes = N - (b << 7); if (nNodes > 128) nNodes = 128;
    int limit = nNodes * 8;
    size_t base4 = ((size_t)b << 7) * 8;
    for (int i = tid; i < limit; i += 256) {
        float4 v = X4[base4 + i];
        float d = sdinv[i >> 3];
        float4 o; o.x = v.x * d; o.y = v.y * d; o.z = v.z * d; o.w = v.w * d;
        Y4[base4 + i] = o;
    }
}

// ---------------- fused per-layer kernel (edge-parallel Phase A) ----------------
// Block = 128 nodes, 256 threads = 32 slots x 8 lanes.
// Phase A: init Xs (stride 33 -> ds_add banks spread by dlow) with self rows;
//   each slot streams the block's CONTIGUOUS ebuf segment (stride 32),
//   2-deep pipelined on ebuf AND Y; per edge: one 128B Y row read + 4
//   native ds_add_f32. No pads, no per-node chains, no shfl trees, no overflow.
// Phase B: scale rows by dinv.  Phase C: 4-node W-reuse gates (unchanged).
__global__ __launch_bounds__(256) void k_layer(const float4* __restrict__ Yin4,
                                               const int2* __restrict__ ebuf,
                                               const int* __restrict__ bbase,
                                               const float* __restrict__ dinv,
                                               const float* __restrict__ cw,
                                               const float* __restrict__ cb,
                                               const float* __restrict__ wc,
                                               const float* __restrict__ bg,
                                               float* __restrict__ outRaw,
                                               float* __restrict__ outY,
                                               int N, int l, int isLast) {
    __shared__ float Ws[32][96];                   // [k][gate*32 + c]
    __shared__ float Xs[128 * 33];                 // stride 33: bank-spread rows
    __shared__ float bS[96];
    __shared__ float wcs[32];
    __shared__ float sdv[128];
    int tid = threadIdx.x;
    int row0 = blockIdx.x * 128;
    // ---- stage Ws, biases, dinv ----
    for (int i = tid; i < 3072; i += 256) {
        int k = i / 96, ccol = i - k * 96;
        int g = ccol >> 5, o = ccol & 31;
        int j = (g == 0) ? 0 : ((g == 1) ? 4 : 6); // I, T, O convs on x
        Ws[k][ccol] = cw[(((l * 8 + j) * 32) + k) * 32 + o];
    }
    if (tid < 32) {
        int c = tid;
        bS[c]      = cb[((l * 8 + 0) * 32) + c] + cb[((l * 8 + 1) * 32) + c] + bg[((l * 4 + 0) * 32) + c];
        bS[32 + c] = cb[((l * 8 + 4) * 32) + c] + cb[((l * 8 + 5) * 32) + c] + bg[((l * 4 + 2) * 32) + c];
        bS[64 + c] = cb[((l * 8 + 6) * 32) + c] + cb[((l * 8 + 7) * 32) + c] + bg[((l * 4 + 3) * 32) + c];
        wcs[c]     = wc[((l * 3 + 2) * 32) + c];
    }
    if (tid < 128) {
        int gr = row0 + tid;
        sdv[tid] = (gr < N) ? dinv[gr] : 0.f;
    }
    // ---- init Xs with raw self rows (scaled by dinv later) ----
    {
        const float* Yf = (const float*)Yin4;
        for (int i = tid; i < 4096; i += 256) {
            int r = i >> 5, k = i & 31;
            int gr = row0 + r;
            Xs[r * 33 + k] = (gr < N) ? Yf[(size_t)gr * 32 + k] : 0.f;
        }
    }
    __syncthreads();
    // ---- Phase A: edge-parallel accumulate, 2-deep pipelined ----
    {
        int slot = tid >> 3, c4 = tid & 7;
        int beg = bbase[blockIdx.x], end = bbase[blockIdx.x + 1];
        int e = slot + beg;
        int2 c0, p1;
        float4 y0;
        if (e < end) {
            c0 = ebuf[e];
            p1 = (e + 32 < end) ? ebuf[e + 32] : c0;
            y0 = Yin4[(size_t)(c0.x & 0x00FFFFFF) * 8 + c4];
        }
        while (e < end) {
            int2 cn = p1;
            if (e + 64 < end) p1 = ebuf[e + 64];
            // issue next Y while current ds_adds wait on y0 (addr valid even at tail)
            int srcn = cn.x & 0x00FFFFFF;
            float4 yn = Yin4[(size_t)srcn * 8 + c4];
            float w = __int_as_float(c0.y);
            int ba = (int)(((unsigned)c0.x) >> 24) * 33 + c4 * 4;
            unsafeAtomicAdd(&Xs[ba + 0], w * y0.x);
            unsafeAtomicAdd(&Xs[ba + 1], w * y0.y);
            unsafeAtomicAdd(&Xs[ba + 2], w * y0.z);
            unsafeAtomicAdd(&Xs[ba + 3], w * y0.w);
            c0 = cn; y0 = yn;
            e += 32;
        }
    }
    __syncthreads();
    // ---- Phase B: scale rows by dinv ----
    for (int i = tid; i < 4096; i += 256) {
        int r = i >> 5;
        Xs[r * 33 + (i & 31)] *= sdv[r];
    }
    __syncthreads();
    // ---- Phase C: gates (4-node W-reuse) ----
    int r0 = tid >> 3, g8 = tid & 7, cbase = g8 * 4;
    float aI[4][4], aT[4][4], aO[4][4];
#pragma unroll
    for (int j = 0; j < 4; j++)
#pragma unroll
        for (int cc = 0; cc < 4; cc++) { aI[j][cc] = 0.f; aT[j][cc] = 0.f; aO[j][cc] = 0.f; }
#pragma unroll 4
    for (int k = 0; k < 32; k++) {
        float4 wI = *(const float4*)&Ws[k][cbase];
        float4 wT = *(const float4*)&Ws[k][32 + cbase];
        float4 wO = *(const float4*)&Ws[k][64 + cbase];
#pragma unroll
        for (int j = 0; j < 4; j++) {
            float xv = Xs[(r0 + 32 * j) * 33 + k];
            aI[j][0] += xv * wI.x; aI[j][1] += xv * wI.y; aI[j][2] += xv * wI.z; aI[j][3] += xv * wI.w;
            aT[j][0] += xv * wT.x; aT[j][1] += xv * wT.y; aT[j][2] += xv * wT.z; aT[j][3] += xv * wT.w;
            aO[j][0] += xv * wO.x; aO[j][1] += xv * wO.y; aO[j][2] += xv * wO.z; aO[j][3] += xv * wO.w;
        }
    }
#pragma unroll
    for (int j = 0; j < 4; j++) {
        int r = r0 + 32 * j;
        int gn = row0 + r;
        if (gn >= N) continue;
        float di = sdv[r];
        float4 v;
        float res[4];
#pragma unroll
        for (int cc = 0; cc < 4; cc++) {
            int c = cbase + cc;
            float I = fsig(aI[j][cc] + bS[c]);
            float T = ftanh(aT[j][cc] + bS[32 + c]);
            float C = I * T;                       // C_old = 0, F-gate dead
            float O = fsig(aO[j][cc] + wcs[c] * C + bS[64 + c]);
            float val = O * ftanh(C);
            res[cc] = isLast ? val : di * val;
        }
        v.x = res[0]; v.y = res[1]; v.z = res[2]; v.w = res[3];
        float* dst = isLast ? outRaw : outY;
        *(float4*)&dst[(size_t)gn * 32 + cbase] = v;
    }
}

extern "C" void kernel_launch(void* const* d_in, const int* in_sizes, int n_in,
                              void* d_out, int out_size, void* d_ws, size_t ws_size,
                              hipStream_t stream) {
    const float* X  = (const float*)d_in[0];
    const int*   ei = (const int*)d_in[1];
    const float* ew = (const float*)d_in[2];
    const float* cw = (const float*)d_in[3];
    const float* cb = (const float*)d_in[4];
    const float* wc = (const float*)d_in[5];
    const float* bg = (const float*)d_in[6];
    int N = in_sizes[0] / 32;
    int E = in_sizes[2];
    int L = in_sizes[3] / (8 * 32 * 32);
    float* out = (float*)d_out;
    int NB = (N + 127) >> 7;                      // 128-node buckets == layer blocks

    char* p = (char*)d_ws;
    auto alloc = [&](size_t bytes) -> char* {
        char* r = p; p += (bytes + 255) & ~(size_t)255; return r;
    };
    int*   bhist     = (int*)alloc((size_t)NB * 4);
    int*   bbase     = (int*)alloc((size_t)(NB + 1) * 4);
    int*   bfill     = (int*)alloc((size_t)NB * 4);
    float* dinv      = (float*)alloc((size_t)N * 4);
    int2*  ebuf      = (int2*)alloc((size_t)E * 8);
    float* Ya        = (float*)alloc((size_t)N * 32 * 4);
    float* Yb        = (float*)alloc((size_t)N * 32 * 4);

    k_zero<<<(NB + 255) / 256, 256, 0, stream>>>(bhist, NB);
    k_bhist<<<512, 256, 0, stream>>>(ei, bhist, E, NB);
    k_bscan<<<1, 256, 0, stream>>>(bhist, bbase, bfill, NB, E);
    int nBin = (E + 4095) / 4096;
    k_bin<<<nBin, 256, 0, stream>>>(ei, ew, bfill, ebuf, E, NB);
    k_bucket<<<NB, 256, 0, stream>>>(ebuf, bbase, dinv,
                                     (const float4*)X, (float4*)Ya, N, E);

    for (int l = 0; l < L; l++) {
        const float* Yin = (l & 1) ? Yb : Ya;
        float*       Ynx = (l & 1) ? Ya : Yb;
        k_layer<<<NB, 256, 0, stream>>>((const float4*)Yin, ebuf, bbase, dinv,
                                        cw, cb, wc, bg,
                                        out, Ynx, N, l, l == L - 1);
    }
}

// Round 22
// 218.827 us; speedup vs baseline: 5.1612x; 5.1612x over previous
//
#include <hip/hip_runtime.h>
#include <math.h>

#define TPB 256
#define NBMAX 2048          // buckets of 256 nodes -> supports N <= 524288

__device__ __forceinline__ float fsig(float x) {
    return __builtin_amdgcn_rcpf(1.f + __expf(-x));   // abs err ~1e-7; x->-inf => 0
}
__device__ __forceinline__ float ftanh(float x) {
    float t = __expf(2.f * fabsf(x));                  // t -> inf => r -> 1
    float r = 1.f - 2.f * __builtin_amdgcn_rcpf(t + 1.f);
    return copysignf(r, x);
}

__global__ __launch_bounds__(256) void k_zero(int* __restrict__ p, int n) {
    int i = blockIdx.x * 256 + threadIdx.x;
    if (i < n) p[i] = 0;
}

// ---------------- bucketed slot-table build (round-12 proven) ----------------

__global__ __launch_bounds__(256) void k_bhist(const int* __restrict__ ei,
                                               int* __restrict__ bhist, int E, int NB) {
    __shared__ int h[NBMAX];
    for (int i = threadIdx.x; i < NB; i += 256) h[i] = 0;
    __syncthreads();
    int stride = gridDim.x * 256;
    for (int e = blockIdx.x * 256 + threadIdx.x; e < E; e += stride)
        atomicAdd(&h[ei[E + e] >> 8], 1);
    __syncthreads();
    for (int i = threadIdx.x; i < NB; i += 256) if (h[i]) atomicAdd(&bhist[i], h[i]);
}

__global__ __launch_bounds__(256) void k_bscan(const int* __restrict__ bhist,
                                               int* __restrict__ bbase, int* __restrict__ bfill,
                                               int NB, int E) {
    __shared__ int tsum[256];
    int tid = threadIdx.x;
    int per = (NB + 255) / 256;           // <= 8
    int loc[8]; int tot = 0;
    int base = tid * per;
#pragma unroll
    for (int j = 0; j < 8; j++) {
        int i = base + j;
        int v = (j < per && i < NB) ? bhist[i] : 0;
        loc[j] = v; tot += v;
    }
    tsum[tid] = tot;
    __syncthreads();
    for (int off = 1; off < 256; off <<= 1) {
        int t = (tid >= off) ? tsum[tid - off] : 0;
        __syncthreads();
        tsum[tid] += t;
        __syncthreads();
    }
    int run = tsum[tid] - tot;
#pragma unroll
    for (int j = 0; j < 8; j++) {
        int i = base + j;
        if (j < per && i < NB) { bbase[i] = run; bfill[i] = run; run += loc[j]; }
    }
    if (tid == 0) bbase[NB] = E;
}

__global__ __launch_bounds__(256) void k_bin(const int* __restrict__ ei,
                                             const float* __restrict__ ew,
                                             int* bfill, int2* __restrict__ ebuf,
                                             int E, int NB) {
    __shared__ int h[NBMAX];
    __shared__ int gb[NBMAX];
    const int EPT = 16;
    int tid = threadIdx.x;
    int base = blockIdx.x * 256 * EPT;
    for (int i = tid; i < NB; i += 256) h[i] = 0;
    __syncthreads();
    int src[EPT]; float w[EPT]; int bkt[EPT]; int lrank[EPT];
#pragma unroll
    for (int j = 0; j < EPT; j++) {
        int e = base + j * 256 + tid;              // coalesced
        if (e < E) {
            src[j] = ei[e]; int d = ei[E + e]; w[j] = ew[e];
            int b = d >> 8;
            bkt[j] = b | ((d & 255) << 16);
            lrank[j] = atomicAdd(&h[b], 1);
        } else bkt[j] = -1;
    }
    __syncthreads();
    for (int i = tid; i < NB; i += 256) gb[i] = h[i] ? atomicAdd(&bfill[i], h[i]) : 0;
    __syncthreads();
#pragma unroll
    for (int j = 0; j < EPT; j++) {
        if (bkt[j] >= 0) {
            int b = bkt[j] & 0xFFFF, dlow = (bkt[j] >> 16) & 0xFF;
            int2 v; v.x = src[j] | (dlow << 24); v.y = __float_as_int(w[j]);
            ebuf[gb[b] + lrank[j]] = v;
        }
    }
}

// per bucket (256 nodes): native LDS atomics for count/weight-sum; scatter
// rank<32 into slot table esl, rank>=32 to overflow list; pad; dinv; Y=dinv*X.
__global__ __launch_bounds__(256) void k_bucket(const int2* __restrict__ ebuf,
                                                const int* __restrict__ bbase,
                                                int2* __restrict__ esl,
                                                int4* __restrict__ ovbuf,
                                                int* __restrict__ ovcnt,
                                                float* __restrict__ dinv,
                                                const float4* __restrict__ X4,
                                                float4* __restrict__ Y4,
                                                int N, int E) {
    __shared__ int lcnt[256];
    __shared__ float wsum[256];
    __shared__ float sdinv[256];
    int b = blockIdx.x, tid = threadIdx.x;
    int beg = bbase[b], end = bbase[b + 1];
    lcnt[tid] = 0; wsum[tid] = 0.f;
    __syncthreads();
    size_t nodeBase = (size_t)(b << 8) * 32;
    for (int i = beg + tid; i < end; i += 256) {
        int2 v = ebuf[i];
        int dlow = ((unsigned)v.x) >> 24;
        unsafeAtomicAdd(&wsum[dlow], __int_as_float(v.y));   // native ds_add_f32
        int rank = atomicAdd(&lcnt[dlow], 1);                // native ds_add_u32
        int2 o; o.x = v.x & 0x00FFFFFF; o.y = v.y;
        if (rank < 32) {
            esl[nodeBase + dlow * 32 + rank] = o;
        } else {                                             // rare overflow
            int oi = atomicAdd(ovcnt, 1);
            int4 q; q.x = o.x; q.y = (b << 8) + dlow; q.z = o.y; q.w = 0;
            ovbuf[oi] = q;
        }
    }
    __syncthreads();                               // lcnt = deg, wsum = sum(w)
    float dv = rsqrtf(1.0f + wsum[tid]);           // self-loop weight 1; deg >= 1
    sdinv[tid] = dv;
    int node = (b << 8) + tid;
    if (node < N) dinv[node] = dv;
    int nNodes = N - (b << 8); if (nNodes > 256) nNodes = 256;
    for (int i = tid; i < nNodes * 32; i += 256) {
        int r = i >> 5, j = i & 31;
        if (j >= lcnt[r]) { int2 z; z.x = 0; z.y = 0; esl[nodeBase + i] = z; }
    }
    int limit = nNodes * 8;
    size_t base4 = ((size_t)b << 8) * 8;
    for (int i = tid; i < limit; i += 256) {
        float4 v = X4[base4 + i];
        float d = sdinv[i >> 3];
        float4 o; o.x = v.x * d; o.y = v.y * d; o.z = v.z * d; o.w = v.w * d;
        Y4[base4 + i] = o;
    }
}

// ---------------- fused per-layer kernel ----------------
// Block = 128 nodes, 256 threads (R18 best-measured configuration, 219.3 us).
// Phase A: 4 waves x 32 nodes, 3-stream pipeline with Y loads issued one
//   node ahead of use (parity-indexed register sets, fully unrolled);
//   the compiler keeps the issue ORDER (the measured win) even where it
//   re-sinks some loads — do NOT pin with sched_barrier (R19: regression),
//   do NOT deepen (R19), do NOT go edge-parallel LDS-atomic (R7/R21).
// Phase B: wave 0 applies overflow edges (deg>32) to Xs.
// Phase C: 4-node W-reuse gates from LDS.
__global__ __launch_bounds__(256) void k_layer(const float4* __restrict__ Yin4,
                                               const int2* __restrict__ esl,
                                               const float* __restrict__ dinv,
                                               const int4* __restrict__ ovbuf,
                                               const int* __restrict__ ovcnt,
                                               const float* __restrict__ cw,
                                               const float* __restrict__ cb,
                                               const float* __restrict__ wc,
                                               const float* __restrict__ bg,
                                               float* __restrict__ outRaw,
                                               float* __restrict__ outY,
                                               int N, int l, int isLast) {
    __shared__ float Ws[32][96];                   // [k][gate*32 + c]
    __shared__ float Xs[128][36];                  // stride 36: 16B-aligned rows
    __shared__ float bS[96];
    __shared__ float wcs[32];
    __shared__ float sdv[128];
    int tid = threadIdx.x;
    int row0 = blockIdx.x * 128;
    // ---- stage Ws, biases, dinv ----
    for (int i = tid; i < 3072; i += 256) {
        int k = i / 96, ccol = i - k * 96;
        int g = ccol >> 5, o = ccol & 31;
        int j = (g == 0) ? 0 : ((g == 1) ? 4 : 6); // I, T, O convs on x
        Ws[k][ccol] = cw[(((l * 8 + j) * 32) + k) * 32 + o];
    }
    if (tid < 32) {
        int c = tid;
        bS[c]      = cb[((l * 8 + 0) * 32) + c] + cb[((l * 8 + 1) * 32) + c] + bg[((l * 4 + 0) * 32) + c];
        bS[32 + c] = cb[((l * 8 + 4) * 32) + c] + cb[((l * 8 + 5) * 32) + c] + bg[((l * 4 + 2) * 32) + c];
        bS[64 + c] = cb[((l * 8 + 6) * 32) + c] + cb[((l * 8 + 7) * 32) + c] + bg[((l * 4 + 3) * 32) + c];
        wcs[c]     = wc[((l * 3 + 2) * 32) + c];
    }
    if (tid < 128) {
        int gr = row0 + tid;
        sdv[tid] = (gr < N) ? dinv[gr] : 0.f;
    }
    __syncthreads();
    // ---- Phase A ----
    int wv = tid >> 6, lane = tid & 63;
    int q = lane >> 3, c4 = lane & 7;
    int nbase = wv * 32;
    int2  sl[2][4];          // esl slots, parity by node
    float wgt_[2][4];        // extracted weights
    float4 sfl[2];           // self rows
    float4 yv[2][4];         // Y data, parity by node
    {   // prologue: esl(0)+self(0), esl(1)+self(1), w(0), Y(0)
        int n0 = row0 + nbase;     int cc0 = (n0 < N) ? n0 : (N - 1);
        int n1 = n0 + 1;           int cc1 = (n1 < N) ? n1 : (N - 1);
        const int2* e0 = esl + (size_t)cc0 * 32 + q;
        sl[0][0] = e0[0]; sl[0][1] = e0[8]; sl[0][2] = e0[16]; sl[0][3] = e0[24];
        sfl[0] = Yin4[(size_t)cc0 * 8 + c4];
        const int2* e1 = esl + (size_t)cc1 * 32 + q;
        sl[1][0] = e1[0]; sl[1][1] = e1[8]; sl[1][2] = e1[16]; sl[1][3] = e1[24];
        sfl[1] = Yin4[(size_t)cc1 * 8 + c4];
#pragma unroll
        for (int j = 0; j < 4; j++) wgt_[0][j] = __int_as_float(sl[0][j].y);
#pragma unroll
        for (int j = 0; j < 4; j++) yv[0][j] = Yin4[(size_t)sl[0][j].x * 8 + c4];
    }
#pragma unroll
    for (int n = 0; n < 32; ++n) {
        const int cur = n & 1, nxt = (n + 1) & 1;
        // 1. weights for node n+1 (waits esl(n+1); Y(n) issued after -> stays in flight)
        if (n + 1 < 32) {
#pragma unroll
            for (int j = 0; j < 4; j++) wgt_[nxt][j] = __int_as_float(sl[nxt][j].y);
        }
        // 2. consume self(n) before its regs are clobbered
        float4 acc1;
        if (q == 0) acc1 = sfl[cur];
        else { acc1.x = 0.f; acc1.y = 0.f; acc1.z = 0.f; acc1.w = 0.f; }
        // 3. issue esl(n+2) + self(n+2) into the dead 'cur' slot set
        if (n + 2 < 32) {
            int m = row0 + nbase + n + 2; int cm = (m < N) ? m : (N - 1);
            const int2* em = esl + (size_t)cm * 32 + q;
            sl[cur][0] = em[0]; sl[cur][1] = em[8]; sl[cur][2] = em[16]; sl[cur][3] = em[24];
            sfl[cur] = Yin4[(size_t)cm * 8 + c4];
        }
        // 4. issue Y(n+1) (addresses from step 1's slot set; newer than esl(n+2))
        if (n + 1 < 32) {
#pragma unroll
            for (int j = 0; j < 4; j++) yv[nxt][j] = Yin4[(size_t)sl[nxt][j].x * 8 + c4];
        }
        // 5. compute node n from Y issued one iteration ago
        float4 acc2; acc2.x = 0.f; acc2.y = 0.f; acc2.z = 0.f; acc2.w = 0.f;
        float w0 = wgt_[cur][0], w1 = wgt_[cur][1], w2 = wgt_[cur][2], w3 = wgt_[cur][3];
        acc1.x += w0 * yv[cur][0].x; acc1.y += w0 * yv[cur][0].y; acc1.z += w0 * yv[cur][0].z; acc1.w += w0 * yv[cur][0].w;
        acc2.x += w1 * yv[cur][1].x; acc2.y += w1 * yv[cur][1].y; acc2.z += w1 * yv[cur][1].z; acc2.w += w1 * yv[cur][1].w;
        acc1.x += w2 * yv[cur][2].x; acc1.y += w2 * yv[cur][2].y; acc1.z += w2 * yv[cur][2].z; acc1.w += w2 * yv[cur][2].w;
        acc2.x += w3 * yv[cur][3].x; acc2.y += w3 * yv[cur][3].y; acc2.z += w3 * yv[cur][3].z; acc2.w += w3 * yv[cur][3].w;
        acc1.x += acc2.x; acc1.y += acc2.y; acc1.z += acc2.z; acc1.w += acc2.w;
#pragma unroll
        for (int off = 8; off <= 32; off <<= 1) {
            acc1.x += __shfl_xor(acc1.x, off);
            acc1.y += __shfl_xor(acc1.y, off);
            acc1.z += __shfl_xor(acc1.z, off);
            acc1.w += __shfl_xor(acc1.w, off);
        }
        int gn = row0 + nbase + n;
        if (gn < N && lane < 8) {
            float di = sdv[nbase + n];
            float4 o; o.x = acc1.x * di; o.y = acc1.y * di;
            o.z = acc1.z * di; o.w = acc1.w * di;
            *(float4*)&Xs[nbase + n][c4 * 4] = o;
        }
    }
    __syncthreads();
    // ---- Phase B: overflow edges (deg>32), wave 0 only, serial (rare) ----
    if (wv == 0) {
        const float* Yf = (const float*)Yin4;
        int cnt = *ovcnt;
        for (int i = 0; i < cnt; i++) {
            int4 qv = ovbuf[i];
            int d = qv.y;
            if (d >= row0 && d < row0 + 128 && d < N) {
                int nb = d - row0;
                float w = __int_as_float(qv.z) * sdv[nb];
                if (lane < 32)
                    Xs[nb][lane] += w * Yf[(size_t)qv.x * 32 + lane];
            }
        }
    }
    __syncthreads();
    // ---- Phase C: gates (4-node W-reuse) ----
    int r0 = tid >> 3, g8 = tid & 7, cbase = g8 * 4;
    float aI[4][4], aT[4][4], aO[4][4];
#pragma unroll
    for (int j = 0; j < 4; j++)
#pragma unroll
        for (int cc = 0; cc < 4; cc++) { aI[j][cc] = 0.f; aT[j][cc] = 0.f; aO[j][cc] = 0.f; }
#pragma unroll 4
    for (int k = 0; k < 32; k++) {
        float4 wI = *(const float4*)&Ws[k][cbase];
        float4 wT = *(const float4*)&Ws[k][32 + cbase];
        float4 wO = *(const float4*)&Ws[k][64 + cbase];
#pragma unroll
        for (int j = 0; j < 4; j++) {
            float xv = Xs[r0 + 32 * j][k];
            aI[j][0] += xv * wI.x; aI[j][1] += xv * wI.y; aI[j][2] += xv * wI.z; aI[j][3] += xv * wI.w;
            aT[j][0] += xv * wT.x; aT[j][1] += xv * wT.y; aT[j][2] += xv * wT.z; aT[j][3] += xv * wT.w;
            aO[j][0] += xv * wO.x; aO[j][1] += xv * wO.y; aO[j][2] += xv * wO.z; aO[j][3] += xv * wO.w;
        }
    }
#pragma unroll
    for (int j = 0; j < 4; j++) {
        int r = r0 + 32 * j;
        int gn = row0 + r;
        if (gn >= N) continue;
        float di = sdv[r];
        float4 v;
        float res[4];
#pragma unroll
        for (int cc = 0; cc < 4; cc++) {
            int c = cbase + cc;
            float I = fsig(aI[j][cc] + bS[c]);
            float T = ftanh(aT[j][cc] + bS[32 + c]);
            float C = I * T;                       // C_old = 0, F-gate dead
            float O = fsig(aO[j][cc] + wcs[c] * C + bS[64 + c]);
            float val = O * ftanh(C);
            res[cc] = isLast ? val : di * val;
        }
        v.x = res[0]; v.y = res[1]; v.z = res[2]; v.w = res[3];
        float* dst = isLast ? outRaw : outY;
        *(float4*)&dst[(size_t)gn * 32 + cbase] = v;
    }
}

extern "C" void kernel_launch(void* const* d_in, const int* in_sizes, int n_in,
                              void* d_out, int out_size, void* d_ws, size_t ws_size,
                              hipStream_t stream) {
    const float* X  = (const float*)d_in[0];
    const int*   ei = (const int*)d_in[1];
    const float* ew = (const float*)d_in[2];
    const float* cw = (const float*)d_in[3];
    const float* cb = (const float*)d_in[4];
    const float* wc = (const float*)d_in[5];
    const float* bg = (const float*)d_in[6];
    int N = in_sizes[0] / 32;
    int E = in_sizes[2];
    int L = in_sizes[3] / (8 * 32 * 32);
    float* out = (float*)d_out;
    int NB = (N + 255) >> 8;                      // 256-node buckets

    char* p = (char*)d_ws;
    auto alloc = [&](size_t bytes) -> char* {
        char* r = p; p += (bytes + 255) & ~(size_t)255; return r;
    };
    int*   bhist     = (int*)alloc((size_t)(NB + 1) * 4);   // [NB] = ovcnt
    int*   bbase     = (int*)alloc((size_t)(NB + 1) * 4);
    int*   bfill     = (int*)alloc((size_t)NB * 4);
    float* dinv      = (float*)alloc((size_t)N * 4);
    int2*  ebuf      = (int2*)alloc((size_t)E * 8);
    int2*  esl       = (int2*)alloc((size_t)N * 32 * 8);
    int4*  ovbuf     = (int4*)alloc((size_t)65536 * 16);
    float* Ya        = (float*)alloc((size_t)N * 32 * 4);
    float* Yb        = (float*)alloc((size_t)N * 32 * 4);
    int*   ovcnt     = bhist + NB;

    k_zero<<<(NB + 256) / 256, 256, 0, stream>>>(bhist, NB + 1);
    k_bhist<<<512, 256, 0, stream>>>(ei, bhist, E, NB);
    k_bscan<<<1, 256, 0, stream>>>(bhist, bbase, bfill, NB, E);
    int nBin = (E + 4095) / 4096;
    k_bin<<<nBin, 256, 0, stream>>>(ei, ew, bfill, ebuf, E, NB);
    k_bucket<<<NB, 256, 0, stream>>>(ebuf, bbase, esl, ovbuf, ovcnt, dinv,
                                     (const float4*)X, (float4*)Ya, N, E);

    int NBL = (N + 127) / 128;
    for (int l = 0; l < L; l++) {
        const float* Yin = (l & 1) ? Yb : Ya;
        float*       Ynx = (l & 1) ? Ya : Yb;
        k_layer<<<NBL, 256, 0, stream>>>((const float4*)Yin, esl, dinv,
                                         ovbuf, ovcnt, cw, cb, wc, bg,
                                         out, Ynx, N, l, l == L - 1);
    }
}